// Round 1
// baseline (393.022 us; speedup 1.0000x reference)
//
#include <hip/hip_runtime.h>

#define BATCH  8
#define SEQ    2048
#define DIMSZ  1024
#define NST    16
#define LCH    32               // chunk length
#define CPB    (SEQ / LCH)      // 64 chunks per batch
#define NCHUNK (BATCH * CPB)    // 512

// ---------------------------------------------------------------------------
// k1: delta[b,s] = sigmoid(gate . dt_w + dt_b) ; Bu[b,s,:] = u[b,s,:] @ B_mat
// block = 256 threads handles 16 consecutive s for one batch.
// thread owns d-quad d0 = tid*4; B rows cached in registers across the 16 s.
// ---------------------------------------------------------------------------
__global__ __launch_bounds__(256) void k1_delta_bu(
    const float* __restrict__ u, const float* __restrict__ gate,
    const float* __restrict__ B_mat, const float* __restrict__ dt_w,
    const float* __restrict__ dt_b,
    float* __restrict__ delta, float* __restrict__ Bu)
{
    __shared__ float red[4 * 17];
    const int tid  = threadIdx.x;
    const int lane = tid & 63;
    const int wv   = tid >> 6;
    const int b    = blockIdx.x >> 7;          // 128 tiles of 16 s per batch
    const int s0   = (blockIdx.x & 127) * 16;
    const int d0   = tid * 4;

    float br[4][NST];
#pragma unroll
    for (int r = 0; r < 4; ++r) {
        const float4* rowp = (const float4*)(B_mat + (size_t)(d0 + r) * NST);
#pragma unroll
        for (int q = 0; q < 4; ++q) {
            float4 v = rowp[q];
            br[r][q*4+0] = v.x; br[r][q*4+1] = v.y;
            br[r][q*4+2] = v.z; br[r][q*4+3] = v.w;
        }
    }
    const float4 wv4 = ((const float4*)dt_w)[tid];
    const float  dtb = dt_b[0];

    for (int si = 0; si < 16; ++si) {
        const int s = s0 + si;
        const size_t row = ((size_t)b * SEQ + s) * DIMSZ;
        const float4 uv = ((const float4*)(u    + row))[tid];
        const float4 gv = ((const float4*)(gate + row))[tid];
        float dacc = gv.x*wv4.x + gv.y*wv4.y + gv.z*wv4.z + gv.w*wv4.w;
        float acc[NST];
#pragma unroll
        for (int n = 0; n < NST; ++n)
            acc[n] = fmaf(uv.x, br[0][n], fmaf(uv.y, br[1][n],
                     fmaf(uv.z, br[2][n], uv.w * br[3][n])));
        // wave64 butterfly reduce (17 values)
#pragma unroll
        for (int k = 1; k < 64; k <<= 1) {
            dacc += __shfl_xor(dacc, k, 64);
#pragma unroll
            for (int n = 0; n < NST; ++n)
                acc[n] += __shfl_xor(acc[n], k, 64);
        }
        if (lane == 0) {
#pragma unroll
            for (int n = 0; n < NST; ++n) red[wv*17 + n] = acc[n];
            red[wv*17 + 16] = dacc;
        }
        __syncthreads();
        if (tid < 17) {
            const float v = red[tid] + red[17 + tid] + red[34 + tid] + red[51 + tid];
            const size_t m = (size_t)b * SEQ + s;
            if (tid < 16) Bu[m * NST + tid] = v;
            else          delta[m] = 1.0f / (1.0f + expf(-(v + dtb)));
        }
        __syncthreads();
    }
}

// ---------------------------------------------------------------------------
// k2: M[m] = expm(delta[m] * A),  A = -exp(A_log).
// One block per timestep; thread = element (i,j). Taylor deg 8 on X = dA/64,
// then 6 squarings. LDS padded to 17 to keep reads conflict-light.
// ---------------------------------------------------------------------------
__global__ __launch_bounds__(256) void k2_expm(
    const float* __restrict__ A_log, const float* __restrict__ delta,
    float* __restrict__ M)
{
    __shared__ float Xs[16 * 17];
    __shared__ float Ts[16 * 17];
    const int tid = threadIdx.x;
    const int i = tid >> 4, j = tid & 15;
    const size_t m = blockIdx.x;
    const float dl = delta[m];
    const float a  = -expf(A_log[tid]);     // accurate exp: growth-mode sensitive
    const float x  = dl * a * (1.0f / 64.0f);   // s = 6  ->  ||X||_1 <= 0.26
    Xs[i*17 + j] = x;
    Ts[i*17 + j] = x;                        // T_1 = X
    float S = x + (i == j ? 1.0f : 0.0f);    // I + X
    __syncthreads();
#pragma unroll
    for (int k = 2; k <= 8; ++k) {           // T_k = T_{k-1} * X / k
        float nt = 0.f;
#pragma unroll
        for (int kk = 0; kk < 16; ++kk)
            nt = fmaf(Ts[i*17 + kk], Xs[kk*17 + j], nt);
        nt *= (1.0f / (float)k);
        S += nt;
        __syncthreads();
        Ts[i*17 + j] = nt;
        __syncthreads();
    }
#pragma unroll
    for (int r = 0; r < 6; ++r) {            // S <- S*S, six times
        __syncthreads();
        Ts[i*17 + j] = S;
        __syncthreads();
        float nt = 0.f;
#pragma unroll
        for (int kk = 0; kk < 16; ++kk)
            nt = fmaf(Ts[i*17 + kk], Ts[kk*17 + j], nt);
        S = nt;
    }
    M[m * 256 + tid] = S;
}

// ---------------------------------------------------------------------------
// k3: per chunk of 32 steps, tree-combine (M,b) pairs:
//   (M1,b1)o(M2,b2) = (M1*M2, b1*M2 + b2)   (left = earlier in time)
// ping-pong LDS buffers, one barrier per level.
// Outputs P[chunk] (16x16) and e[chunk] (16).
// ---------------------------------------------------------------------------
__global__ __launch_bounds__(256) void k3_chunk(
    const float* __restrict__ M, const float* __restrict__ Bu,
    float* __restrict__ P, float* __restrict__ e)
{
    __shared__ float X[LCH * 256];           // 32 KB
    __shared__ float Y[(LCH/2) * 256];       // 16 KB
    __shared__ float bx[LCH * NST];
    __shared__ float by[(LCH/2) * NST];
    const int tid = threadIdx.x;
    const size_t g = blockIdx.x;
    const float* Mg = M + g * (size_t)(LCH * 256);
    for (int idx = tid; idx < LCH*256; idx += 256) X[idx] = Mg[idx];
    const float* Bg = Bu + g * (size_t)(LCH * NST);
    for (int idx = tid; idx < LCH*NST; idx += 256) bx[idx] = Bg[idx];
    __syncthreads();
    float* src = X;  float* dst = Y;
    float* bs  = bx; float* bd  = by;
    int n = LCH / 2;
    while (n >= 1) {
        for (int idx = tid; idx < n*256; idx += 256) {
            const int p = idx >> 8, ij = idx & 255, i = ij >> 4, j = ij & 15;
            const float* Ap = src + (size_t)(2*p)     * 256;
            const float* Bp = src + (size_t)(2*p + 1) * 256;
            float c = 0.f;
#pragma unroll
            for (int k = 0; k < 16; ++k)
                c = fmaf(Ap[i*16 + k], Bp[k*16 + j], c);
            dst[idx] = c;
        }
        for (int idx = tid; idx < n*NST; idx += 256) {
            const int p = idx >> 4, j = idx & 15;
            const float* Bp = src + (size_t)(2*p + 1) * 256;
            float c = bs[(2*p + 1)*16 + j];
#pragma unroll
            for (int k = 0; k < 16; ++k)
                c = fmaf(bs[(2*p)*16 + k], Bp[k*16 + j], c);
            bd[idx] = c;
        }
        __syncthreads();
        float* t = src; src = dst; dst = t;
        t = bs; bs = bd; bd = t;
        n >>= 1;
    }
    P[g * 256 + tid] = src[tid];
    if (tid < NST) e[g * NST + tid] = bs[tid];
}

// ---------------------------------------------------------------------------
// k4: serial scan over the 64 chunk summaries of each batch.
// hin[chunk] = state entering that chunk.  8 blocks; wave 0 does the scan.
// ---------------------------------------------------------------------------
__global__ __launch_bounds__(256) void k4_scan(
    const float* __restrict__ P, const float* __restrict__ e,
    float* __restrict__ hin)
{
    __shared__ float Pl[32 * 272];
    __shared__ float el[32 * NST];
    const int tid = threadIdx.x;
    const int b = blockIdx.x;
    float h = 0.f;
    for (int half = 0; half < 2; ++half) {
        const int c0 = half * 32;
        for (int idx = tid; idx < 32*256; idx += 256) {
            const int c = idx >> 8, ij = idx & 255, i = ij >> 4, jj = ij & 15;
            Pl[c*272 + i*17 + jj] = P[((size_t)(b*CPB + c0 + c)) * 256 + ij];
        }
        for (int idx = tid; idx < 32*NST; idx += 256)
            el[idx] = e[((size_t)(b*CPB + c0)) * NST + idx];
        __syncthreads();
        if (tid < 64) {
            const int j = tid & 15;
            for (int c = 0; c < 32; ++c) {
                if (tid < 16) hin[((size_t)(b*CPB + c0 + c)) * NST + j] = h;
                float hn = el[c*16 + j];
#pragma unroll
                for (int i2 = 0; i2 < 16; ++i2)
                    hn = fmaf(__shfl(h, i2, 64), Pl[c*272 + i2*17 + j], hn);
                h = hn;
            }
        }
        __syncthreads();
    }
}

// ---------------------------------------------------------------------------
// k5: per chunk, replay recurrence from hin (wave 0), then fused projection
//     y[b,s,:] = h_s @ C^T + D*u[b,s,:].  C rows live in registers.
// ---------------------------------------------------------------------------
__global__ __launch_bounds__(256) void k5_output(
    const float* __restrict__ M, const float* __restrict__ Bu,
    const float* __restrict__ hin, const float* __restrict__ u,
    const float* __restrict__ C_mat, const float* __restrict__ D,
    float* __restrict__ y)
{
    __shared__ float Ml[LCH * 272];
    __shared__ float Bus[LCH * NST];
    __shared__ __align__(16) float Hs[LCH * NST];
    const int tid = threadIdx.x;
    const size_t g = blockIdx.x;
    const int b = (int)(g >> 6);             // CPB = 64 chunks/batch
    const int c = (int)(g & 63);
    const int s0 = c * LCH;
    const float* Mg = M + g * (size_t)(LCH * 256);
    for (int idx = tid; idx < LCH*256; idx += 256) {
        const int t = idx >> 8, ij = idx & 255, i = ij >> 4, j = ij & 15;
        Ml[t*272 + i*17 + j] = Mg[idx];
    }
    for (int idx = tid; idx < LCH*NST; idx += 256)
        Bus[idx] = Bu[g * (size_t)(LCH*NST) + idx];
    __syncthreads();
    if (tid < 64) {
        const int j = tid & 15;
        float h = hin[g * NST + j];
        for (int t = 0; t < LCH; ++t) {
            float hn = Bus[t*16 + j];
#pragma unroll
            for (int i2 = 0; i2 < 16; ++i2)
                hn = fmaf(__shfl(h, i2, 64), Ml[t*272 + i2*17 + j], hn);
            h = hn;
            if (tid < 16) Hs[t*16 + j] = h;
        }
    }
    __syncthreads();
    const int d0 = tid * 4;
    float4 cr[4][4];
#pragma unroll
    for (int r = 0; r < 4; ++r)
#pragma unroll
        for (int q = 0; q < 4; ++q)
            cr[r][q] = ((const float4*)C_mat)[(d0 + r) * 4 + q];
    const float4 dv = ((const float4*)D)[tid];
    for (int t = 0; t < LCH; ++t) {
        const int s = s0 + t;
        const size_t row = ((size_t)b * SEQ + s) * DIMSZ;
        const float4 uv = ((const float4*)(u + row))[tid];
        float y0 = dv.x * uv.x, y1 = dv.y * uv.y, y2 = dv.z * uv.z, y3 = dv.w * uv.w;
#pragma unroll
        for (int q = 0; q < 4; ++q) {
            const float4 hq = *((const float4*)&Hs[t*16 + q*4]);
            y0 = fmaf(hq.x, cr[0][q].x, y0); y0 = fmaf(hq.y, cr[0][q].y, y0);
            y0 = fmaf(hq.z, cr[0][q].z, y0); y0 = fmaf(hq.w, cr[0][q].w, y0);
            y1 = fmaf(hq.x, cr[1][q].x, y1); y1 = fmaf(hq.y, cr[1][q].y, y1);
            y1 = fmaf(hq.z, cr[1][q].z, y1); y1 = fmaf(hq.w, cr[1][q].w, y1);
            y2 = fmaf(hq.x, cr[2][q].x, y2); y2 = fmaf(hq.y, cr[2][q].y, y2);
            y2 = fmaf(hq.z, cr[2][q].z, y2); y2 = fmaf(hq.w, cr[2][q].w, y2);
            y3 = fmaf(hq.x, cr[3][q].x, y3); y3 = fmaf(hq.y, cr[3][q].y, y3);
            y3 = fmaf(hq.z, cr[3][q].z, y3); y3 = fmaf(hq.w, cr[3][q].w, y3);
        }
        float4 ov; ov.x = y0; ov.y = y1; ov.z = y2; ov.w = y3;
        ((float4*)(y + row))[tid] = ov;
    }
}

// ---------------------------------------------------------------------------
extern "C" void kernel_launch(void* const* d_in, const int* in_sizes, int n_in,
                              void* d_out, int out_size, void* d_ws, size_t ws_size,
                              hipStream_t stream)
{
    const float* u     = (const float*)d_in[0];
    const float* gate  = (const float*)d_in[1];
    const float* A_log = (const float*)d_in[2];
    const float* B_mat = (const float*)d_in[3];
    const float* C_mat = (const float*)d_in[4];
    const float* D     = (const float*)d_in[5];
    const float* dt_w  = (const float*)d_in[6];
    const float* dt_b  = (const float*)d_in[7];
    float* y = (float*)d_out;

    // workspace layout (floats): ~18.5 MB total
    float* ws    = (float*)d_ws;
    float* delta = ws;                                   // BATCH*SEQ
    float* Bu    = delta + (size_t)BATCH*SEQ;            // BATCH*SEQ*NST
    float* M     = Bu    + (size_t)BATCH*SEQ*NST;        // BATCH*SEQ*256
    float* P     = M     + (size_t)BATCH*SEQ*NST*NST;    // NCHUNK*256
    float* e     = P     + (size_t)NCHUNK*256;           // NCHUNK*16
    float* hin   = e     + (size_t)NCHUNK*NST;           // NCHUNK*16

    k1_delta_bu<<<BATCH*SEQ/16, 256, 0, stream>>>(u, gate, B_mat, dt_w, dt_b, delta, Bu);
    k2_expm    <<<BATCH*SEQ,    256, 0, stream>>>(A_log, delta, M);
    k3_chunk   <<<NCHUNK,       256, 0, stream>>>(M, Bu, P, e);
    k4_scan    <<<BATCH,        256, 0, stream>>>(P, e, hin);
    k5_output  <<<NCHUNK,       256, 0, stream>>>(M, Bu, hin, u, C_mat, D, y);
}

// Round 2
// 309.340 us; speedup vs baseline: 1.2705x; 1.2705x over previous
//
#include <hip/hip_runtime.h>

#define BATCH  8
#define SEQ    2048
#define DIMSZ  1024
#define NST    16
#define LCH    32               // chunk length
#define CPB    (SEQ / LCH)      // 64 chunks per batch
#define NCHUNK (BATCH * CPB)    // 512
#define NCHEB  32               // Chebyshev terms (degree 31)

typedef __attribute__((ext_vector_type(8))) short bf16x8;
typedef __attribute__((ext_vector_type(4))) float f32x4;

static __device__ __forceinline__ unsigned short f2bf(float f) {
    unsigned u = __builtin_bit_cast(unsigned, f);
    unsigned r = (u + 0x7FFFu + ((u >> 16) & 1u)) >> 16;
    return (unsigned short)r;
}
static __device__ __forceinline__ float bf2f(unsigned short h) {
    unsigned u = ((unsigned)h) << 16;
    return __builtin_bit_cast(float, u);
}

// ---------------------------------------------------------------------------
// s0: F_k = expm(delta_k * A) at the 32 Chebyshev nodes delta_k in (0,1).
// Same scaling-and-squaring as the verified k2 (Taylor-8, s=6). 32 blocks.
// ---------------------------------------------------------------------------
__global__ __launch_bounds__(256) void s0_nodes(
    const float* __restrict__ A_log, float* __restrict__ Fn)
{
    __shared__ float Xs[16 * 17];
    __shared__ float Ts[16 * 17];
    const int tid = threadIdx.x;
    const int i = tid >> 4, j = tid & 15;
    const float th = (2.f * blockIdx.x + 1.f) * (3.14159265358979f / 64.f);
    const float dl = 0.5f * (1.f + cosf(th));
    const float a  = -expf(A_log[tid]);
    const float x  = dl * a * (1.0f / 64.0f);     // s = 6
    Xs[i*17 + j] = x;
    Ts[i*17 + j] = x;
    float S = x + (i == j ? 1.0f : 0.0f);
    __syncthreads();
#pragma unroll
    for (int k = 2; k <= 8; ++k) {
        float nt = 0.f;
#pragma unroll
        for (int kk = 0; kk < 16; ++kk)
            nt = fmaf(Ts[i*17 + kk], Xs[kk*17 + j], nt);
        nt *= (1.0f / (float)k);
        S += nt;
        __syncthreads();
        Ts[i*17 + j] = nt;
        __syncthreads();
    }
#pragma unroll
    for (int r = 0; r < 6; ++r) {
        __syncthreads();
        Ts[i*17 + j] = S;
        __syncthreads();
        float nt = 0.f;
#pragma unroll
        for (int kk = 0; kk < 16; ++kk)
            nt = fmaf(Ts[i*17 + kk], Ts[kk*17 + j], nt);
        S = nt;
    }
    Fn[(size_t)blockIdx.x * 256 + tid] = S;
}

// ---------------------------------------------------------------------------
// s1: Chebyshev coefficient matrices G_m = scale * sum_k F_k cos(m theta_k),
// stored thread-major Gt[element][m] so consumers load 8 float4 per thread.
// ---------------------------------------------------------------------------
__global__ __launch_bounds__(256) void s1_cheb(
    const float* __restrict__ Fn, float* __restrict__ Gt)
{
    const int tid = threadIdx.x;
    float acc[NCHEB];
#pragma unroll
    for (int m = 0; m < NCHEB; ++m) acc[m] = 0.f;
    for (int k = 0; k < NCHEB; ++k) {
        const float f  = Fn[(size_t)k * 256 + tid];
        const float th = (2.f * k + 1.f) * (3.14159265358979f / 64.f);
        const float c1 = cosf(th);
        float cm2 = 1.f, cm1 = c1;
        acc[0] += f;
        acc[1] = fmaf(f, c1, acc[1]);
#pragma unroll
        for (int m = 2; m < NCHEB; ++m) {
            const float cm = fmaf(2.f * c1, cm1, -cm2);
            acc[m] = fmaf(f, cm, acc[m]);
            cm2 = cm1; cm1 = cm;
        }
    }
    Gt[(size_t)tid * NCHEB + 0] = acc[0] * (1.f / 32.f);
#pragma unroll
    for (int m = 1; m < NCHEB; ++m)
        Gt[(size_t)tid * NCHEB + m] = acc[m] * (2.f / 32.f);
}

// ---------------------------------------------------------------------------
// s2: pre-swizzle B_mat and dt_w into MFMA B-operand fragments (bf16 hi/lo).
// Fragment element (ks, lane, j): k = ks*32 + (lane>>4)*8 + j, n = lane&15.
// ---------------------------------------------------------------------------
__global__ __launch_bounds__(256) void s2_frag(
    const float* __restrict__ B_mat, const float* __restrict__ dt_w,
    unsigned short* __restrict__ Bfh, unsigned short* __restrict__ Bfl,
    unsigned short* __restrict__ Wfh, unsigned short* __restrict__ Wfl)
{
    const int tid = threadIdx.x;
    for (int idx = tid; idx < 32 * 64 * 8; idx += 256) {
        const int j  = idx & 7;
        const int l  = (idx >> 3) & 63;
        const int ks = idx >> 9;
        const int k  = ks * 32 + ((l >> 4) << 3) + j;
        const int n  = l & 15;
        float bv = B_mat[(size_t)k * 16 + n];
        unsigned short h = f2bf(bv);
        Bfh[idx] = h;
        Bfl[idx] = f2bf(bv - bf2f(h));
        float wv = (n == 0) ? dt_w[k] : 0.f;
        h = f2bf(wv);
        Wfh[idx] = h;
        Wfl[idx] = f2bf(wv - bf2f(h));
    }
}

// ---------------------------------------------------------------------------
// k1: Bu = u @ B and delta-dot via bf16-split MFMA (3 terms: hi*hi+hi*lo+lo*hi).
// Wave handles 16 tokens; no cross-lane reductions at all.
// ---------------------------------------------------------------------------
__global__ __launch_bounds__(256) void k1_mfma(
    const float* __restrict__ u, const float* __restrict__ gate,
    const unsigned short* __restrict__ Bfh, const unsigned short* __restrict__ Bfl,
    const unsigned short* __restrict__ Wfh, const unsigned short* __restrict__ Wfl,
    const float* __restrict__ dt_b,
    float* __restrict__ delta, float* __restrict__ Bu)
{
    const int tid  = threadIdx.x;
    const int lane = tid & 63;
    const int wv   = tid >> 6;
    const size_t m0 = (size_t)blockIdx.x * 64 + wv * 16;
    const int mrow = lane & 15;
    const int q    = lane >> 4;
    const float* up = u    + (m0 + mrow) * DIMSZ + q * 8;
    const float* gp = gate + (m0 + mrow) * DIMSZ + q * 8;
    const uint4* bh = (const uint4*)Bfh;
    const uint4* bl = (const uint4*)Bfl;
    const uint4* wh = (const uint4*)Wfh;
    const uint4* wl = (const uint4*)Wfl;

    f32x4 acc0 = {0.f, 0.f, 0.f, 0.f};
    f32x4 acc1 = {0.f, 0.f, 0.f, 0.f};
    for (int ks = 0; ks < 32; ++ks) {
        const float4 a0 = *(const float4*)(up + ks * 32);
        const float4 a1 = *(const float4*)(up + ks * 32 + 4);
        const float4 g0 = *(const float4*)(gp + ks * 32);
        const float4 g1 = *(const float4*)(gp + ks * 32 + 4);
        float fu[8] = {a0.x, a0.y, a0.z, a0.w, a1.x, a1.y, a1.z, a1.w};
        float fg[8] = {g0.x, g0.y, g0.z, g0.w, g1.x, g1.y, g1.z, g1.w};
        bf16x8 uh, ul, gh, gl;
#pragma unroll
        for (int i = 0; i < 8; ++i) {
            unsigned short h = f2bf(fu[i]);
            uh[i] = (short)h; ul[i] = (short)f2bf(fu[i] - bf2f(h));
            h = f2bf(fg[i]);
            gh[i] = (short)h; gl[i] = (short)f2bf(fg[i] - bf2f(h));
        }
        const bf16x8 Bh = __builtin_bit_cast(bf16x8, bh[ks * 64 + lane]);
        const bf16x8 Bl = __builtin_bit_cast(bf16x8, bl[ks * 64 + lane]);
        const bf16x8 Wh = __builtin_bit_cast(bf16x8, wh[ks * 64 + lane]);
        const bf16x8 Wl = __builtin_bit_cast(bf16x8, wl[ks * 64 + lane]);
        acc0 = __builtin_amdgcn_mfma_f32_16x16x32_bf16(uh, Bh, acc0, 0, 0, 0);
        acc0 = __builtin_amdgcn_mfma_f32_16x16x32_bf16(uh, Bl, acc0, 0, 0, 0);
        acc0 = __builtin_amdgcn_mfma_f32_16x16x32_bf16(ul, Bh, acc0, 0, 0, 0);
        acc1 = __builtin_amdgcn_mfma_f32_16x16x32_bf16(gh, Wh, acc1, 0, 0, 0);
        acc1 = __builtin_amdgcn_mfma_f32_16x16x32_bf16(gh, Wl, acc1, 0, 0, 0);
        acc1 = __builtin_amdgcn_mfma_f32_16x16x32_bf16(gl, Wh, acc1, 0, 0, 0);
    }
    const int n  = lane & 15;
    const int rb = q * 4;
#pragma unroll
    for (int r = 0; r < 4; ++r)
        Bu[(m0 + rb + r) * NST + n] = acc0[r];
    if (n == 0) {
        const float dtb = dt_b[0];
#pragma unroll
        for (int r = 0; r < 4; ++r)
            delta[m0 + rb + r] = 1.0f / (1.0f + expf(-(acc1[r] + dtb)));
    }
}

// ---------------------------------------------------------------------------
// kA: per chunk — M_t via register-resident Chebyshev eval (no LDS matmuls),
// e_c via serial wave-0 replay, P_c = F(sum/32)^32 (5 LDS squarings).
// ---------------------------------------------------------------------------
__global__ __launch_bounds__(256) void kA_chunk(
    const float* __restrict__ Gt, const float* __restrict__ delta,
    const float* __restrict__ Bu,
    float* __restrict__ P, float* __restrict__ e)
{
    __shared__ float dl[LCH];
    __shared__ float sd[1];
    __shared__ float Bus[LCH * NST];
    __shared__ float Mlds[LCH * 256];
    __shared__ float Ps[16 * 17];
    const int tid = threadIdx.x;
    const size_t g = blockIdx.x;
    if (tid < LCH) dl[tid] = delta[g * LCH + tid];
    for (int idx = tid; idx < LCH * NST; idx += 256)
        Bus[idx] = Bu[g * (size_t)(LCH * NST) + idx];
    float gr[NCHEB];
    {
        const float4* gp = (const float4*)(Gt + (size_t)tid * NCHEB);
#pragma unroll
        for (int qq = 0; qq < NCHEB / 4; ++qq) {
            float4 v = gp[qq];
            gr[qq*4+0] = v.x; gr[qq*4+1] = v.y; gr[qq*4+2] = v.z; gr[qq*4+3] = v.w;
        }
    }
    __syncthreads();
    if (tid == 0) {
        float s = 0.f;
        for (int t = 0; t < LCH; ++t) s += dl[t];
        sd[0] = s;
    }
    for (int t = 0; t < LCH; ++t) {
        const float x = 2.f * dl[t] - 1.f;
        float acc = fmaf(gr[1], x, gr[0]);
        float tm2 = 1.f, tm1 = x;
#pragma unroll
        for (int m = 2; m < NCHEB; ++m) {
            const float tm = fmaf(2.f * x, tm1, -tm2);
            acc = fmaf(gr[m], tm, acc);
            tm2 = tm1; tm1 = tm;
        }
        Mlds[t * 256 + tid] = acc;
    }
    __syncthreads();
    // P_c = F(sum/32)^32
    float S;
    {
        const float xp = 2.f * (sd[0] * (1.f / LCH)) - 1.f;
        float acc = fmaf(gr[1], xp, gr[0]);
        float tm2 = 1.f, tm1 = xp;
#pragma unroll
        for (int m = 2; m < NCHEB; ++m) {
            const float tm = fmaf(2.f * xp, tm1, -tm2);
            acc = fmaf(gr[m], tm, acc);
            tm2 = tm1; tm1 = tm;
        }
        S = acc;
    }
    const int i = tid >> 4, j = tid & 15;
#pragma unroll
    for (int r = 0; r < 5; ++r) {
        Ps[i*17 + j] = S;
        __syncthreads();
        float ns = 0.f;
#pragma unroll
        for (int k = 0; k < 16; ++k)
            ns = fmaf(Ps[i*17 + k], Ps[k*17 + j], ns);
        __syncthreads();
        S = ns;
    }
    P[g * 256 + tid] = S;
    // serial replay from zero -> e_c (wave 0, lanes 0..15)
    if (tid < 16) {
        float h = 0.f;
        for (int t = 0; t < LCH; ++t) {
            float hn = Bus[t * 16 + tid];
#pragma unroll
            for (int i2 = 0; i2 < 16; ++i2)
                hn = fmaf(__shfl(h, i2, 64), Mlds[t * 256 + i2 * 16 + tid], hn);
            h = hn;
        }
        e[g * NST + tid] = h;
    }
}

// ---------------------------------------------------------------------------
// k4: serial scan over the 64 chunk summaries of each batch (unchanged).
// ---------------------------------------------------------------------------
__global__ __launch_bounds__(256) void k4_scan(
    const float* __restrict__ P, const float* __restrict__ e,
    float* __restrict__ hin)
{
    __shared__ float Pl[32 * 272];
    __shared__ float el[32 * NST];
    const int tid = threadIdx.x;
    const int b = blockIdx.x;
    float h = 0.f;
    for (int half = 0; half < 2; ++half) {
        const int c0 = half * 32;
        for (int idx = tid; idx < 32*256; idx += 256) {
            const int c = idx >> 8, ij = idx & 255, i = ij >> 4, jj = ij & 15;
            Pl[c*272 + i*17 + jj] = P[((size_t)(b*CPB + c0 + c)) * 256 + ij];
        }
        for (int idx = tid; idx < 32*NST; idx += 256)
            el[idx] = e[((size_t)(b*CPB + c0)) * NST + idx];
        __syncthreads();
        if (tid < 64) {
            const int j = tid & 15;
            for (int c = 0; c < 32; ++c) {
                if (tid < 16) hin[((size_t)(b*CPB + c0 + c)) * NST + j] = h;
                float hn = el[c*16 + j];
#pragma unroll
                for (int i2 = 0; i2 < 16; ++i2)
                    hn = fmaf(__shfl(h, i2, 64), Pl[c*272 + i2*17 + j], hn);
                h = hn;
            }
        }
        __syncthreads();
    }
}

// ---------------------------------------------------------------------------
// k5: recompute M from delta (register Chebyshev), replay from hin, fused
// projection y = h C^T + D*u.
// ---------------------------------------------------------------------------
__global__ __launch_bounds__(256) void k5_out(
    const float* __restrict__ Gt, const float* __restrict__ delta,
    const float* __restrict__ Bu, const float* __restrict__ hin,
    const float* __restrict__ u, const float* __restrict__ C_mat,
    const float* __restrict__ D, float* __restrict__ y)
{
    __shared__ float dl[LCH];
    __shared__ float Bus[LCH * NST];
    __shared__ float Mlds[LCH * 256];
    __shared__ __align__(16) float Hs[LCH * NST];
    const int tid = threadIdx.x;
    const size_t g = blockIdx.x;
    if (tid < LCH) dl[tid] = delta[g * LCH + tid];
    for (int idx = tid; idx < LCH * NST; idx += 256)
        Bus[idx] = Bu[g * (size_t)(LCH * NST) + idx];
    float gr[NCHEB];
    {
        const float4* gp = (const float4*)(Gt + (size_t)tid * NCHEB);
#pragma unroll
        for (int qq = 0; qq < NCHEB / 4; ++qq) {
            float4 v = gp[qq];
            gr[qq*4+0] = v.x; gr[qq*4+1] = v.y; gr[qq*4+2] = v.z; gr[qq*4+3] = v.w;
        }
    }
    __syncthreads();
    for (int t = 0; t < LCH; ++t) {
        const float x = 2.f * dl[t] - 1.f;
        float acc = fmaf(gr[1], x, gr[0]);
        float tm2 = 1.f, tm1 = x;
#pragma unroll
        for (int m = 2; m < NCHEB; ++m) {
            const float tm = fmaf(2.f * x, tm1, -tm2);
            acc = fmaf(gr[m], tm, acc);
            tm2 = tm1; tm1 = tm;
        }
        Mlds[t * 256 + tid] = acc;
    }
    __syncthreads();
    if (tid < 16) {
        float h = hin[g * NST + tid];
        for (int t = 0; t < LCH; ++t) {
            float hn = Bus[t * 16 + tid];
#pragma unroll
            for (int i2 = 0; i2 < 16; ++i2)
                hn = fmaf(__shfl(h, i2, 64), Mlds[t * 256 + i2 * 16 + tid], hn);
            h = hn;
            Hs[t * 16 + tid] = h;
        }
    }
    __syncthreads();
    const int d0 = tid * 4;
    float4 cr[4][4];
#pragma unroll
    for (int r = 0; r < 4; ++r)
#pragma unroll
        for (int qq = 0; qq < 4; ++qq)
            cr[r][qq] = ((const float4*)C_mat)[(d0 + r) * 4 + qq];
    const float4 dv = ((const float4*)D)[tid];
    for (int t = 0; t < LCH; ++t) {
        const size_t row = (g * LCH + t) * DIMSZ;
        const float4 uv = ((const float4*)(u + row))[tid];
        float y0 = dv.x * uv.x, y1 = dv.y * uv.y, y2 = dv.z * uv.z, y3 = dv.w * uv.w;
#pragma unroll
        for (int qq = 0; qq < 4; ++qq) {
            const float4 hq = *((const float4*)&Hs[t*16 + qq*4]);
            y0 = fmaf(hq.x, cr[0][qq].x, y0); y0 = fmaf(hq.y, cr[0][qq].y, y0);
            y0 = fmaf(hq.z, cr[0][qq].z, y0); y0 = fmaf(hq.w, cr[0][qq].w, y0);
            y1 = fmaf(hq.x, cr[1][qq].x, y1); y1 = fmaf(hq.y, cr[1][qq].y, y1);
            y1 = fmaf(hq.z, cr[1][qq].z, y1); y1 = fmaf(hq.w, cr[1][qq].w, y1);
            y2 = fmaf(hq.x, cr[2][qq].x, y2); y2 = fmaf(hq.y, cr[2][qq].y, y2);
            y2 = fmaf(hq.z, cr[2][qq].z, y2); y2 = fmaf(hq.w, cr[2][qq].w, y2);
            y3 = fmaf(hq.x, cr[3][qq].x, y3); y3 = fmaf(hq.y, cr[3][qq].y, y3);
            y3 = fmaf(hq.z, cr[3][qq].z, y3); y3 = fmaf(hq.w, cr[3][qq].w, y3);
        }
        float4 ov; ov.x = y0; ov.y = y1; ov.z = y2; ov.w = y3;
        ((float4*)(y + row))[tid] = ov;
    }
}

// ---------------------------------------------------------------------------
extern "C" void kernel_launch(void* const* d_in, const int* in_sizes, int n_in,
                              void* d_out, int out_size, void* d_ws, size_t ws_size,
                              hipStream_t stream)
{
    const float* u     = (const float*)d_in[0];
    const float* gate  = (const float*)d_in[1];
    const float* A_log = (const float*)d_in[2];
    const float* B_mat = (const float*)d_in[3];
    const float* C_mat = (const float*)d_in[4];
    const float* D     = (const float*)d_in[5];
    const float* dt_w  = (const float*)d_in[6];
    const float* dt_b  = (const float*)d_in[7];
    float* y = (float*)d_out;

    float* ws = (float*)d_ws;
    size_t o = 0;
    float* Fn    = ws + o; o += 32 * 256;                 // node expm values
    float* Gt    = ws + o; o += 256 * NCHEB;              // Chebyshev coeffs (thread-major)
    float* delta = ws + o; o += (size_t)BATCH * SEQ;
    float* Bu    = ws + o; o += (size_t)BATCH * SEQ * NST;
    float* P     = ws + o; o += (size_t)NCHUNK * 256;
    float* e     = ws + o; o += (size_t)NCHUNK * NST;
    float* hin   = ws + o; o += (size_t)NCHUNK * NST;
    unsigned short* Bfh = (unsigned short*)(ws + o); o += 8192;   // 16384 ushort each
    unsigned short* Bfl = (unsigned short*)(ws + o); o += 8192;
    unsigned short* Wfh = (unsigned short*)(ws + o); o += 8192;
    unsigned short* Wfl = (unsigned short*)(ws + o); o += 8192;

    s0_nodes<<<NCHEB, 256, 0, stream>>>(A_log, Fn);
    s1_cheb <<<1,     256, 0, stream>>>(Fn, Gt);
    s2_frag <<<1,     256, 0, stream>>>(B_mat, dt_w, Bfh, Bfl, Wfh, Wfl);
    k1_mfma <<<BATCH * SEQ / 64, 256, 0, stream>>>(u, gate, Bfh, Bfl, Wfh, Wfl,
                                                   dt_b, delta, Bu);
    kA_chunk<<<NCHUNK, 256, 0, stream>>>(Gt, delta, Bu, P, e);
    k4_scan <<<BATCH,  256, 0, stream>>>(P, e, hin);
    k5_out  <<<NCHUNK, 256, 0, stream>>>(Gt, delta, Bu, hin, u, C_mat, D, y);
}

// Round 3
// 272.006 us; speedup vs baseline: 1.4449x; 1.1373x over previous
//
#include <hip/hip_runtime.h>

#define BATCH  8
#define SEQ    2048
#define DIMSZ  1024
#define NST    16
#define LCH    32               // chunk length
#define CPB    (SEQ / LCH)      // 64 chunks per batch
#define NCHUNK (BATCH * CPB)    // 512
#define NCHEB  32               // Chebyshev terms (degree 31)

typedef __attribute__((ext_vector_type(8))) short bf16x8;
typedef __attribute__((ext_vector_type(4))) float f32x4;

static __device__ __forceinline__ unsigned short f2bf(float f) {
    unsigned u = __builtin_bit_cast(unsigned, f);
    unsigned r = (u + 0x7FFFu + ((u >> 16) & 1u)) >> 16;
    return (unsigned short)r;
}
static __device__ __forceinline__ float bf2f(unsigned short h) {
    unsigned u = ((unsigned)h) << 16;
    return __builtin_bit_cast(float, u);
}

// ---------------------------------------------------------------------------
// sA: F_k = expm(delta_k * A) at the 32 Chebyshev nodes delta_k in (0,1).
// Taylor-8 + 6 squarings (verified). 32 blocks.
// ---------------------------------------------------------------------------
__global__ __launch_bounds__(256) void sA_nodes(
    const float* __restrict__ A_log, float* __restrict__ Fn)
{
    __shared__ float Xs[16 * 17];
    __shared__ float Ts[16 * 17];
    const int tid = threadIdx.x;
    const int i = tid >> 4, j = tid & 15;
    const float th = (2.f * blockIdx.x + 1.f) * (3.14159265358979f / 64.f);
    const float dl = 0.5f * (1.f + cosf(th));
    const float a  = -expf(A_log[tid]);
    const float x  = dl * a * (1.0f / 64.0f);     // s = 6
    Xs[i*17 + j] = x;
    Ts[i*17 + j] = x;
    float S = x + (i == j ? 1.0f : 0.0f);
    __syncthreads();
#pragma unroll
    for (int k = 2; k <= 8; ++k) {
        float nt = 0.f;
#pragma unroll
        for (int kk = 0; kk < 16; ++kk)
            nt = fmaf(Ts[i*17 + kk], Xs[kk*17 + j], nt);
        nt *= (1.0f / (float)k);
        S += nt;
        __syncthreads();
        Ts[i*17 + j] = nt;
        __syncthreads();
    }
#pragma unroll
    for (int r = 0; r < 6; ++r) {
        __syncthreads();
        Ts[i*17 + j] = S;
        __syncthreads();
        float nt = 0.f;
#pragma unroll
        for (int kk = 0; kk < 16; ++kk)
            nt = fmaf(Ts[i*17 + kk], Ts[kk*17 + j], nt);
        S = nt;
    }
    Fn[(size_t)blockIdx.x * 256 + tid] = S;
}

// ---------------------------------------------------------------------------
// sB: blocks 0..31  -> Chebyshev coefficient m = blockIdx.x (thread = element)
//     blocks 32..39 -> bf16 hi/lo MFMA B-operand fragments for B_mat / dt_w
// ---------------------------------------------------------------------------
__global__ __launch_bounds__(256) void sB_setup(
    const float* __restrict__ Fn, const float* __restrict__ B_mat,
    const float* __restrict__ dt_w,
    float* __restrict__ Gt,
    unsigned short* __restrict__ Bfh, unsigned short* __restrict__ Bfl,
    unsigned short* __restrict__ Wfh, unsigned short* __restrict__ Wfl)
{
    const int tid = threadIdx.x;
    const int blk = blockIdx.x;
    if (blk < NCHEB) {
        const int m = blk;
        float acc = 0.f;
        for (int k = 0; k < NCHEB; ++k) {
            const float th = (2.f * k + 1.f) * (3.14159265358979f / 64.f);
            acc = fmaf(Fn[(size_t)k * 256 + tid], cosf(m * th), acc);
        }
        const float sc = (m == 0) ? (1.f / 32.f) : (2.f / 32.f);
        Gt[(size_t)tid * NCHEB + m] = acc * sc;
    } else {
        const int idx0 = (blk - NCHEB) * 2048;
        for (int t = 0; t < 8; ++t) {
            const int idx = idx0 + t * 256 + tid;
            const int j  = idx & 7;
            const int l  = (idx >> 3) & 63;
            const int ks = idx >> 9;
            const int k  = ks * 32 + ((l >> 4) << 3) + j;
            const int n  = l & 15;
            float bv = B_mat[(size_t)k * 16 + n];
            unsigned short h = f2bf(bv);
            Bfh[idx] = h;
            Bfl[idx] = f2bf(bv - bf2f(h));
            float wv = (n == 0) ? dt_w[k] : 0.f;
            h = f2bf(wv);
            Wfh[idx] = h;
            Wfl[idx] = f2bf(wv - bf2f(h));
        }
    }
}

// ---------------------------------------------------------------------------
// k1: Bu = u @ B and delta-dot via bf16-split MFMA. Block = 16 tokens;
// 4 waves K-split (each wave K=256), LDS reduce of partial accumulators.
// ---------------------------------------------------------------------------
__global__ __launch_bounds__(256, 4) void k1_mfma(
    const float* __restrict__ u, const float* __restrict__ gate,
    const unsigned short* __restrict__ Bfh, const unsigned short* __restrict__ Bfl,
    const unsigned short* __restrict__ Wfh, const unsigned short* __restrict__ Wfl,
    const float* __restrict__ dt_b,
    float* __restrict__ delta, float* __restrict__ Bu)
{
    __shared__ float r0[4 * 256];
    __shared__ float r1[4 * 256];
    const int tid  = threadIdx.x;
    const int lane = tid & 63;
    const int wv   = tid >> 6;
    const size_t m0 = (size_t)blockIdx.x * 16;
    const int mrow = lane & 15;
    const int q    = lane >> 4;
    const float* up = u    + (m0 + mrow) * DIMSZ + q * 8;
    const float* gp = gate + (m0 + mrow) * DIMSZ + q * 8;
    const uint4* bh = (const uint4*)Bfh;
    const uint4* bl = (const uint4*)Bfl;
    const uint4* wh = (const uint4*)Wfh;
    const uint4* wl = (const uint4*)Wfl;

    f32x4 acc0 = {0.f, 0.f, 0.f, 0.f};
    f32x4 acc1 = {0.f, 0.f, 0.f, 0.f};
    const int ksBase = wv * 8;
    float4 a0 = *(const float4*)(up + ksBase * 32);
    float4 a1 = *(const float4*)(up + ksBase * 32 + 4);
    float4 g0 = *(const float4*)(gp + ksBase * 32);
    float4 g1 = *(const float4*)(gp + ksBase * 32 + 4);
#pragma unroll
    for (int t = 0; t < 8; ++t) {
        const int ks = ksBase + t;
        const float4 b0 = a0, b1 = a1, h0 = g0, h1 = g1;
        if (t < 7) {
            a0 = *(const float4*)(up + (ks + 1) * 32);
            a1 = *(const float4*)(up + (ks + 1) * 32 + 4);
            g0 = *(const float4*)(gp + (ks + 1) * 32);
            g1 = *(const float4*)(gp + (ks + 1) * 32 + 4);
        }
        const bf16x8 Bh = __builtin_bit_cast(bf16x8, bh[ks * 64 + lane]);
        const bf16x8 Bl = __builtin_bit_cast(bf16x8, bl[ks * 64 + lane]);
        const bf16x8 Wh = __builtin_bit_cast(bf16x8, wh[ks * 64 + lane]);
        const bf16x8 Wl = __builtin_bit_cast(bf16x8, wl[ks * 64 + lane]);
        const float fu[8] = {b0.x, b0.y, b0.z, b0.w, b1.x, b1.y, b1.z, b1.w};
        const float fg[8] = {h0.x, h0.y, h0.z, h0.w, h1.x, h1.y, h1.z, h1.w};
        bf16x8 uh, ul, gh, gl;
#pragma unroll
        for (int i = 0; i < 8; ++i) {
            unsigned short h = f2bf(fu[i]);
            uh[i] = (short)h; ul[i] = (short)f2bf(fu[i] - bf2f(h));
            h = f2bf(fg[i]);
            gh[i] = (short)h; gl[i] = (short)f2bf(fg[i] - bf2f(h));
        }
        acc0 = __builtin_amdgcn_mfma_f32_16x16x32_bf16(uh, Bh, acc0, 0, 0, 0);
        acc0 = __builtin_amdgcn_mfma_f32_16x16x32_bf16(uh, Bl, acc0, 0, 0, 0);
        acc0 = __builtin_amdgcn_mfma_f32_16x16x32_bf16(ul, Bh, acc0, 0, 0, 0);
        acc1 = __builtin_amdgcn_mfma_f32_16x16x32_bf16(gh, Wh, acc1, 0, 0, 0);
        acc1 = __builtin_amdgcn_mfma_f32_16x16x32_bf16(gh, Wl, acc1, 0, 0, 0);
        acc1 = __builtin_amdgcn_mfma_f32_16x16x32_bf16(gl, Wh, acc1, 0, 0, 0);
    }
    // C layout: col(n) = lane&15, row(token) = q*4 + r
    const int n = lane & 15;
#pragma unroll
    for (int r = 0; r < 4; ++r) {
        r0[wv * 256 + (q * 4 + r) * 16 + n] = acc0[r];
        r1[wv * 256 + (q * 4 + r) * 16 + n] = acc1[r];
    }
    __syncthreads();
    const float b = r0[tid] + r0[256 + tid] + r0[512 + tid] + r0[768 + tid];
    Bu[m0 * NST + tid] = b;          // (m0 + tid/16)*16 + tid%16 == m0*16 + tid
    if (tid < 16) {
        const float dacc = r1[tid * 16] + r1[256 + tid * 16] +
                           r1[512 + tid * 16] + r1[768 + tid * 16];
        delta[m0 + tid] = 1.0f / (1.0f + expf(-(dacc + dt_b[0])));
    }
}

// ---------------------------------------------------------------------------
// kA: per chunk — M_t via register Chebyshev eval, e_c via wave-0 replay,
// P_c = F(sum/32)^32 (5 LDS squarings).
// ---------------------------------------------------------------------------
__global__ __launch_bounds__(256) void kA_chunk(
    const float* __restrict__ Gt, const float* __restrict__ delta,
    const float* __restrict__ Bu,
    float* __restrict__ P, float* __restrict__ e)
{
    __shared__ float dl[LCH];
    __shared__ float sd[1];
    __shared__ float Bus[LCH * NST];
    __shared__ float Mlds[LCH * 256];
    __shared__ float Ps[16 * 17];
    const int tid = threadIdx.x;
    const size_t g = blockIdx.x;
    if (tid < LCH) dl[tid] = delta[g * LCH + tid];
    for (int idx = tid; idx < LCH * NST; idx += 256)
        Bus[idx] = Bu[g * (size_t)(LCH * NST) + idx];
    float gr[NCHEB];
    {
        const float4* gp = (const float4*)(Gt + (size_t)tid * NCHEB);
#pragma unroll
        for (int qq = 0; qq < NCHEB / 4; ++qq) {
            float4 v = gp[qq];
            gr[qq*4+0] = v.x; gr[qq*4+1] = v.y; gr[qq*4+2] = v.z; gr[qq*4+3] = v.w;
        }
    }
    __syncthreads();
    if (tid == 0) {
        float s = 0.f;
        for (int t = 0; t < LCH; ++t) s += dl[t];
        sd[0] = s;
    }
    for (int t = 0; t < LCH; ++t) {
        const float x = 2.f * dl[t] - 1.f;
        float acc = fmaf(gr[1], x, gr[0]);
        float tm2 = 1.f, tm1 = x;
#pragma unroll
        for (int m = 2; m < NCHEB; ++m) {
            const float tm = fmaf(2.f * x, tm1, -tm2);
            acc = fmaf(gr[m], tm, acc);
            tm2 = tm1; tm1 = tm;
        }
        Mlds[t * 256 + tid] = acc;
    }
    __syncthreads();
    float S;
    {
        const float xp = 2.f * (sd[0] * (1.f / LCH)) - 1.f;
        float acc = fmaf(gr[1], xp, gr[0]);
        float tm2 = 1.f, tm1 = xp;
#pragma unroll
        for (int m = 2; m < NCHEB; ++m) {
            const float tm = fmaf(2.f * xp, tm1, -tm2);
            acc = fmaf(gr[m], tm, acc);
            tm2 = tm1; tm1 = tm;
        }
        S = acc;
    }
    const int i = tid >> 4, j = tid & 15;
#pragma unroll
    for (int r = 0; r < 5; ++r) {
        Ps[i*17 + j] = S;
        __syncthreads();
        float ns = 0.f;
#pragma unroll
        for (int k = 0; k < 16; ++k)
            ns = fmaf(Ps[i*17 + k], Ps[k*17 + j], ns);
        __syncthreads();
        S = ns;
    }
    P[g * 256 + tid] = S;
    if (tid < 16) {
        float h = 0.f;
        for (int t = 0; t < LCH; ++t) {
            float hn = Bus[t * 16 + tid];
#pragma unroll
            for (int i2 = 0; i2 < 16; ++i2)
                hn = fmaf(__shfl(h, i2, 64), Mlds[t * 256 + i2 * 16 + tid], hn);
            h = hn;
        }
        e[g * NST + tid] = h;
    }
}

// ---------------------------------------------------------------------------
// k4: serial scan over the 64 chunk summaries of each batch.
// ---------------------------------------------------------------------------
__global__ __launch_bounds__(256) void k4_scan(
    const float* __restrict__ P, const float* __restrict__ e,
    float* __restrict__ hin)
{
    __shared__ float Pl[32 * 272];
    __shared__ float el[32 * NST];
    const int tid = threadIdx.x;
    const int b = blockIdx.x;
    float h = 0.f;
    for (int half = 0; half < 2; ++half) {
        const int c0 = half * 32;
        for (int idx = tid; idx < 32*256; idx += 256) {
            const int c = idx >> 8, ij = idx & 255, i = ij >> 4, jj = ij & 15;
            Pl[c*272 + i*17 + jj] = P[((size_t)(b*CPB + c0 + c)) * 256 + ij];
        }
        for (int idx = tid; idx < 32*NST; idx += 256)
            el[idx] = e[((size_t)(b*CPB + c0)) * NST + idx];
        __syncthreads();
        if (tid < 64) {
            const int j = tid & 15;
            for (int c = 0; c < 32; ++c) {
                if (tid < 16) hin[((size_t)(b*CPB + c0 + c)) * NST + j] = h;
                float hn = el[c*16 + j];
#pragma unroll
                for (int i2 = 0; i2 < 16; ++i2)
                    hn = fmaf(__shfl(h, i2, 64), Pl[c*272 + i2*17 + j], hn);
                h = hn;
            }
        }
        __syncthreads();
    }
}

// ---------------------------------------------------------------------------
// k5: recompute M from delta (register Chebyshev), replay from hin, fused
// projection y = h C^T + D*u.
// ---------------------------------------------------------------------------
__global__ __launch_bounds__(256) void k5_out(
    const float* __restrict__ Gt, const float* __restrict__ delta,
    const float* __restrict__ Bu, const float* __restrict__ hin,
    const float* __restrict__ u, const float* __restrict__ C_mat,
    const float* __restrict__ D, float* __restrict__ y)
{
    __shared__ float dl[LCH];
    __shared__ float Bus[LCH * NST];
    __shared__ float Mlds[LCH * 256];
    __shared__ __align__(16) float Hs[LCH * NST];
    const int tid = threadIdx.x;
    const size_t g = blockIdx.x;
    if (tid < LCH) dl[tid] = delta[g * LCH + tid];
    for (int idx = tid; idx < LCH * NST; idx += 256)
        Bus[idx] = Bu[g * (size_t)(LCH * NST) + idx];
    float gr[NCHEB];
    {
        const float4* gp = (const float4*)(Gt + (size_t)tid * NCHEB);
#pragma unroll
        for (int qq = 0; qq < NCHEB / 4; ++qq) {
            float4 v = gp[qq];
            gr[qq*4+0] = v.x; gr[qq*4+1] = v.y; gr[qq*4+2] = v.z; gr[qq*4+3] = v.w;
        }
    }
    __syncthreads();
    for (int t = 0; t < LCH; ++t) {
        const float x = 2.f * dl[t] - 1.f;
        float acc = fmaf(gr[1], x, gr[0]);
        float tm2 = 1.f, tm1 = x;
#pragma unroll
        for (int m = 2; m < NCHEB; ++m) {
            const float tm = fmaf(2.f * x, tm1, -tm2);
            acc = fmaf(gr[m], tm, acc);
            tm2 = tm1; tm1 = tm;
        }
        Mlds[t * 256 + tid] = acc;
    }
    __syncthreads();
    if (tid < 16) {
        float h = hin[g * NST + tid];
        for (int t = 0; t < LCH; ++t) {
            float hn = Bus[t * 16 + tid];
#pragma unroll
            for (int i2 = 0; i2 < 16; ++i2)
                hn = fmaf(__shfl(h, i2, 64), Mlds[t * 256 + i2 * 16 + tid], hn);
            h = hn;
            Hs[t * 16 + tid] = h;
        }
    }
    __syncthreads();
    const int d0 = tid * 4;
    float4 cr[4][4];
#pragma unroll
    for (int r = 0; r < 4; ++r)
#pragma unroll
        for (int qq = 0; qq < 4; ++qq)
            cr[r][qq] = ((const float4*)C_mat)[(d0 + r) * 4 + qq];
    const float4 dv = ((const float4*)D)[tid];
    for (int t = 0; t < LCH; ++t) {
        const size_t row = (g * LCH + t) * DIMSZ;
        const float4 uv = ((const float4*)(u + row))[tid];
        float y0 = dv.x * uv.x, y1 = dv.y * uv.y, y2 = dv.z * uv.z, y3 = dv.w * uv.w;
#pragma unroll
        for (int qq = 0; qq < 4; ++qq) {
            const float4 hq = *((const float4*)&Hs[t*16 + qq*4]);
            y0 = fmaf(hq.x, cr[0][qq].x, y0); y0 = fmaf(hq.y, cr[0][qq].y, y0);
            y0 = fmaf(hq.z, cr[0][qq].z, y0); y0 = fmaf(hq.w, cr[0][qq].w, y0);
            y1 = fmaf(hq.x, cr[1][qq].x, y1); y1 = fmaf(hq.y, cr[1][qq].y, y1);
            y1 = fmaf(hq.z, cr[1][qq].z, y1); y1 = fmaf(hq.w, cr[1][qq].w, y1);
            y2 = fmaf(hq.x, cr[2][qq].x, y2); y2 = fmaf(hq.y, cr[2][qq].y, y2);
            y2 = fmaf(hq.z, cr[2][qq].z, y2); y2 = fmaf(hq.w, cr[2][qq].w, y2);
            y3 = fmaf(hq.x, cr[3][qq].x, y3); y3 = fmaf(hq.y, cr[3][qq].y, y3);
            y3 = fmaf(hq.z, cr[3][qq].z, y3); y3 = fmaf(hq.w, cr[3][qq].w, y3);
        }
        float4 ov; ov.x = y0; ov.y = y1; ov.z = y2; ov.w = y3;
        ((float4*)(y + row))[tid] = ov;
    }
}

// ---------------------------------------------------------------------------
extern "C" void kernel_launch(void* const* d_in, const int* in_sizes, int n_in,
                              void* d_out, int out_size, void* d_ws, size_t ws_size,
                              hipStream_t stream)
{
    const float* u     = (const float*)d_in[0];
    const float* gate  = (const float*)d_in[1];
    const float* A_log = (const float*)d_in[2];
    const float* B_mat = (const float*)d_in[3];
    const float* C_mat = (const float*)d_in[4];
    const float* D     = (const float*)d_in[5];
    const float* dt_w  = (const float*)d_in[6];
    const float* dt_b  = (const float*)d_in[7];
    float* y = (float*)d_out;

    float* ws = (float*)d_ws;
    size_t o = 0;
    float* Fn    = ws + o; o += 32 * 256;
    float* Gt    = ws + o; o += 256 * NCHEB;
    float* delta = ws + o; o += (size_t)BATCH * SEQ;
    float* Bu    = ws + o; o += (size_t)BATCH * SEQ * NST;
    float* P     = ws + o; o += (size_t)NCHUNK * 256;
    float* e     = ws + o; o += (size_t)NCHUNK * NST;
    float* hin   = ws + o; o += (size_t)NCHUNK * NST;
    unsigned short* Bfh = (unsigned short*)(ws + o); o += 8192;
    unsigned short* Bfl = (unsigned short*)(ws + o); o += 8192;
    unsigned short* Wfh = (unsigned short*)(ws + o); o += 8192;
    unsigned short* Wfl = (unsigned short*)(ws + o); o += 8192;

    sA_nodes<<<NCHEB, 256, 0, stream>>>(A_log, Fn);
    sB_setup<<<NCHEB + 8, 256, 0, stream>>>(Fn, B_mat, dt_w, Gt, Bfh, Bfl, Wfh, Wfl);
    k1_mfma <<<BATCH * SEQ / 16, 256, 0, stream>>>(u, gate, Bfh, Bfl, Wfh, Wfl,
                                                   dt_b, delta, Bu);
    kA_chunk<<<NCHUNK, 256, 0, stream>>>(Gt, delta, Bu, P, e);
    k4_scan <<<BATCH,  256, 0, stream>>>(P, e, hin);
    k5_out  <<<NCHUNK, 256, 0, stream>>>(Gt, delta, Bu, hin, u, C_mat, D, y);
}